// Round 16
// baseline (78.389 us; speedup 1.0000x reference)
//
#include <hip/hip_runtime.h>
#include <hip/hip_bf16.h>

#define BB 8
#define CC 128
#define NN 4096
#define LOG2E 1.44269504088896340736f

typedef __attribute__((ext_vector_type(4))) float f32x4;
typedef __attribute__((ext_vector_type(4))) short s16x4;
typedef __attribute__((ext_vector_type(8))) short s16x8;

__device__ inline short f2bf(float f){
  unsigned u = __float_as_uint(f);
  u += 0x7FFFu + ((u >> 16) & 1u);
  return (short)(u >> 16);
}
// low16 = bf16(e0), high16 = bf16(e1), truncation
__device__ inline unsigned pack2(float e0, float e1){
  return __builtin_amdgcn_perm(__float_as_uint(e1), __float_as_uint(e0), 0x07060302u);
}

// read one MFMA operand fragment from a swizzled LDS tile:
// element (row, c) lives at byte row*256 + ((c>>2)^(row&31))*8 + (c&3)*2
__device__ inline s16x8 frag_read(const char* base, int row, int kk, int g){
  const int m = row & 31;
  const char* rp = base + row*256;
  s16x4 lo = *(const s16x4*)(rp + (((kk*8 + g)     ^ m) << 3));
  s16x4 hi = *(const s16x4*)(rp + (((kk*8 + 4 + g) ^ m) << 3));
  s16x8 r = {lo[0],lo[1],lo[2],lo[3],hi[0],hi[1],hi[2],hi[3]};
  return r;
}

// ---------------- K1: MFMA projections ----------------
__global__ __launch_bounds__(256) void k_proj(
    const float* __restrict__ x,  const float* __restrict__ Wf, const float* __restrict__ bf,
    const float* __restrict__ Wg, const float* __restrict__ bg,
    const float* __restrict__ Wh, const float* __restrict__ bh,
    short* __restrict__ fT, short* __restrict__ gT, short* __restrict__ hP)
{
  __shared__ __align__(16) char sx[16384];
  __shared__ __align__(16) char sw[40960];

  const int blk = blockIdx.x;
  const int b = blk & 7, ntile = blk >> 3;
  const int n0 = ntile * 64;
  const int tid = threadIdx.x;

  // stage x: c-pair packed u32 writes (2 bf16 per ds_write_b32)
  {
    const int cpair = tid >> 4;           // 0..15
    const int nj = (tid & 15) * 4;        // 0..60
    #pragma unroll
    for (int p = 0; p < 4; ++p){
      const int c0 = p*32 + cpair*2;
      f32x4 v0 = *(const f32x4*)(x + ((size_t)(b*128 + c0    ))*NN + n0 + nj);
      f32x4 v1 = *(const f32x4*)(x + ((size_t)(b*128 + c0 + 1))*NN + n0 + nj);
      #pragma unroll
      for (int e = 0; e < 4; ++e){
        const int n = nj + e;
        const int off = n*256 + ((((c0>>2) ^ (n & 31))) << 3) + ((c0 & 3) << 1);
        *(unsigned*)(sx + off) = pack2(v0[e], v1[e]);
      }
    }
  }
  // stage W, bf16 trunc (Wf scaled by log2e)
  {
    #pragma unroll
    for (int p = 0; p < 20; ++p){
      const int id = p*256 + tid;
      const int row = id >> 5;
      const int q = id & 31;
      const float* src; float scale = 1.0f;
      if (row < 16)      { src = Wf + row*128;      scale = LOG2E; }
      else if (row < 32) { src = Wg + (row-16)*128; }
      else               { src = Wh + (row-32)*128; }
      f32x4 v = *(const f32x4*)(src + q*4);
      unsigned u0 = pack2(v[0]*scale, v[1]*scale);
      unsigned u1 = pack2(v[2]*scale, v[3]*scale);
      const int off = row*256 + ((q ^ (row & 31)) << 3);
      *(unsigned long long*)(sw + off) = ((unsigned long long)u1 << 32) | u0;
    }
  }
  __syncthreads();

  const int w = tid >> 6, l = tid & 63;
  const int g = l >> 4, lm = l & 15;
  const int nn = w*16 + lm;
  const int nglob = n0 + w*16 + lm;

  s16x8 xf[4];
  #pragma unroll
  for (int kk = 0; kk < 4; ++kk) xf[kk] = frag_read(sx, nn, kk, g);

  {
    f32x4 acc;
    f32x4 bv = *(const f32x4*)(bf + 4*g);
    #pragma unroll
    for (int i=0;i<4;++i) acc[i] = bv[i] * LOG2E;
    #pragma unroll
    for (int kk = 0; kk < 4; ++kk)
      acc = __builtin_amdgcn_mfma_f32_16x16x32_bf16(frag_read(sw, lm, kk, g), xf[kk], acc, 0,0,0);
    unsigned u0 = pack2(acc[0], acc[1]);
    unsigned u1 = pack2(acc[2], acc[3]);
    *(unsigned long long*)(fT + ((size_t)b*NN + nglob)*16 + 4*g) = ((unsigned long long)u1 << 32) | u0;
  }
  {
    f32x4 acc = *(const f32x4*)(bg + 4*g);
    #pragma unroll
    for (int kk = 0; kk < 4; ++kk)
      acc = __builtin_amdgcn_mfma_f32_16x16x32_bf16(frag_read(sw, 16+lm, kk, g), xf[kk], acc, 0,0,0);
    unsigned u0 = pack2(acc[0], acc[1]);
    unsigned u1 = pack2(acc[2], acc[3]);
    *(unsigned long long*)(gT + ((size_t)b*NN + nglob)*16 + 4*g) = ((unsigned long long)u1 << 32) | u0;
  }
  {
    const int nc  = ntile*2 + (w >> 1);
    const int tau = w & 1;
    #pragma unroll
    for (int ct = 0; ct < 8; ++ct){
      const float bb = bh[ct*16 + lm];
      f32x4 acc = {bb, bb, bb, bb};
      #pragma unroll
      for (int kk = 0; kk < 4; ++kk)
        acc = __builtin_amdgcn_mfma_f32_16x16x32_bf16(xf[kk], frag_read(sw, 32 + ct*16 + lm, kk, g), acc, 0,0,0);
      unsigned u0 = pack2(acc[0], acc[1]);
      unsigned u1 = pack2(acc[2], acc[3]);
      const int row = ct*64 + g*16 + lm;
      *(unsigned long long*)((char*)hP + (((size_t)(b*128 + nc))*512 + row)*16 + tau*8)
          = ((unsigned long long)u1 << 32) | u0;
    }
  }
}

// ---------------- K2: L[n] = -log2( sum_m exp2(S'[n][m]) ) ----------------
// S-MFMA uses K=16 (16x16x16 bf16) — Cp=16 exactly, no zero-padded K slots (R14 win).
__global__ __launch_bounds__(512,4) void k_stats(
    const short* __restrict__ fT, const short* __restrict__ gT, float* __restrict__ Lrow)
{
  __shared__ float sm[2][4][16];
  const int blk = blockIdx.x;
  const int b = blk & 7, ntile = blk >> 3;
  const int tid = threadIdx.x;
  const int w = tid >> 6, l = tid & 63;
  const int g = l >> 4, lm = l & 15;
  const int ns = w & 3, mh = w >> 2;
  const int n0 = ntile*64 + ns*16;
  const f32x4 zero4 = {0.f,0.f,0.f,0.f};

  s16x4 fa = *(const s16x4*)(fT + ((size_t)b*NN + n0 + lm)*16 + 4*g);

  const short* gTb = gT + ((size_t)b*NN + mh*2048 + lm)*16 + 4*g;

  f32x4 rs = {0.f,0.f,0.f,0.f};
  s16x4 gc[4], gn[4];
  #pragma unroll
  for (int j=0;j<4;++j) gc[j] = *(const s16x4*)(gTb + j*256);

  #pragma unroll 1
  for (int it=0; it<32; ++it){
    const int nx = (it < 31) ? it+1 : 31;
    #pragma unroll
    for (int j=0;j<4;++j) gn[j] = *(const s16x4*)(gTb + nx*1024 + j*256);
    #pragma unroll
    for (int j=0;j<4;++j){
      f32x4 d = __builtin_amdgcn_mfma_f32_16x16x16bf16_1k(fa, gc[j], zero4, 0,0,0);
      #pragma unroll
      for (int i=0;i<4;++i) rs[i] += __builtin_amdgcn_exp2f(d[i]);
    }
    #pragma unroll
    for (int j=0;j<4;++j) gc[j] = gn[j];
  }
  #pragma unroll
  for (int i=0;i<4;++i){
    #pragma unroll
    for (int mask=1; mask<16; mask<<=1) rs[i] += __shfl_xor(rs[i], mask);
  }
  if (lm == 0){
    #pragma unroll
    for (int i=0;i<4;++i) sm[mh][ns][4*g+i] = rs[i];
  }
  __syncthreads();
  if (mh == 0 && lm == 0){
    #pragma unroll
    for (int i=0;i<4;++i){
      float z = rs[i] + sm[1][ns][4*g+i];
      Lrow[(size_t)b*NN + n0 + 4*g + i] = -__log2f(z);
    }
  }
}

// ---------------- K3: out = x + gamma * sum_n h[c][n] * exp2(S'[n][m] + L[n]) ----------------
// grid 1024 = 8b x 64 mtiles x 2 c-halves. block 256 = 4 nq-waves.
// Wave = 64 m x 64 c: acc[4][4] = 64 AGPR -> target 3 waves/SIMD. Same total L2
// hb traffic as R13 (c-halves read disjoint chunk halves). S-phase duplicated per half.
__global__ __launch_bounds__(256,3) void k_attend(
    const float* __restrict__ x, const short* __restrict__ fT, const short* __restrict__ gT,
    const short* __restrict__ hP, const float* __restrict__ Lrow,
    const float* __restrict__ gamma, float* __restrict__ out)
{
  __shared__ __align__(16) char lds[8192];

  const int blk = blockIdx.x;
  const int b = blk & 7;
  const int mtile = (blk >> 3) & 63;
  const int ch = blk >> 9;                 // c-half 0/1
  const int tid = threadIdx.x;
  const int nq = tid >> 6, l = tid & 63;
  const int g = l >> 4, lm = l & 15;
  const int m0w = mtile*64;
  const f32x4 zero4 = {0.f,0.f,0.f,0.f};

  const short* fTb = fT + ((size_t)b*NN + nq*1024 + lm)*16 + 4*g;
  const float* Lb  = Lrow + (size_t)b*NN + nq*1024 + 4*g;
  // fragment rows for this c-half: ch*256 + cs*64 + l  (cs = 0..3)
  const char*  hB  = (const char*)hP + (((size_t)(b*128 + nq*32))*512 + ch*256 + l)*16;

  s16x8 gb[4];
  #pragma unroll
  for (int mt=0; mt<4; ++mt){
    s16x4 g4 = *(const s16x4*)(gT + ((size_t)b*NN + m0w + mt*16 + lm)*16 + 4*g);
    s16x8 t = {g4[0],g4[1],g4[2],g4[3],0,0,0,0};
    gb[mt] = t;
  }

  f32x4 acc[4][4];
  #pragma unroll
  for (int mt=0;mt<4;++mt)
    #pragma unroll
    for (int cs=0;cs<4;++cs) acc[mt][cs] = zero4;

  s16x4 fa_c0 = *(const s16x4*)(fTb);
  s16x4 fa_c1 = *(const s16x4*)(fTb + 256);
  f32x4 C0 = *(const f32x4*)(Lb);
  f32x4 C1 = *(const f32x4*)(Lb + 16);

  #pragma unroll 1
  for (int it=0; it<32; ++it){
    const int nx = (it < 31) ? it+1 : 31;

    // h fragments (this c-half): 4 independent coalesced 1KB loads, issued first;
    // the S/exp2/pack phase below covers their L2 latency.
    s16x8 hb[4];
    #pragma unroll
    for (int cs=0; cs<4; ++cs) hb[cs] = *(const s16x8*)(hB + it*8192 + cs*1024);

    // prefetch fa/L for next chunk (clamped, unconditional)
    s16x4 pfa0 = *(const s16x4*)(fTb + nx*512);
    s16x4 pfa1 = *(const s16x4*)(fTb + nx*512 + 256);
    f32x4 pC0  = *(const f32x4*)(Lb + nx*32);
    f32x4 pC1  = *(const f32x4*)(Lb + nx*32 + 16);

    s16x8 fa0 = {fa_c0[0],fa_c0[1],fa_c0[2],fa_c0[3],0,0,0,0};
    s16x8 fa1 = {fa_c1[0],fa_c1[1],fa_c1[2],fa_c1[3],0,0,0,0};

    __builtin_amdgcn_s_setprio(1);
    s16x8 A[4];
    #pragma unroll
    for (int mt=0; mt<4; ++mt){
      f32x4 d0 = __builtin_amdgcn_mfma_f32_16x16x32_bf16(fa0, gb[mt], C0, 0,0,0);
      f32x4 d1 = __builtin_amdgcn_mfma_f32_16x16x32_bf16(fa1, gb[mt], C1, 0,0,0);
      union { unsigned u[4]; s16x8 v; } P;
      P.u[0] = pack2(__builtin_amdgcn_exp2f(d0[0]), __builtin_amdgcn_exp2f(d0[1]));
      P.u[1] = pack2(__builtin_amdgcn_exp2f(d0[2]), __builtin_amdgcn_exp2f(d0[3]));
      P.u[2] = pack2(__builtin_amdgcn_exp2f(d1[0]), __builtin_amdgcn_exp2f(d1[1]));
      P.u[3] = pack2(__builtin_amdgcn_exp2f(d1[2]), __builtin_amdgcn_exp2f(d1[3]));
      A[mt] = P.v;
    }

    #pragma unroll
    for (int cs=0; cs<4; ++cs){
      #pragma unroll
      for (int mt=0; mt<4; ++mt)
        acc[mt][cs] = __builtin_amdgcn_mfma_f32_16x16x32_bf16(A[mt], hb[cs], acc[mt][cs], 0,0,0);
    }
    __builtin_amdgcn_s_setprio(0);

    fa_c0 = pfa0; fa_c1 = pfa1; C0 = pC0; C1 = pC1;
  }

  // 4-way nq reduction in 4 fully-unrolled mt-phases (static acc indexing)
  float* redA = (float*)lds;             // [4 cs][64 lane][4]
  float* redB = (float*)(lds + 4096);
  const float gm = gamma[0];
  #pragma unroll
  for (int mt=0; mt<4; ++mt){
    if (nq == 1 || nq == 3){
      float* rp = (nq==1)? redA : redB;
      #pragma unroll
      for (int cs=0; cs<4; ++cs)
        *(f32x4*)(rp + (cs*64 + l)*4) = acc[mt][cs];
    }
    __syncthreads();
    if (nq == 0 || nq == 2){
      const float* rp = (nq==0)? redA : redB;
      #pragma unroll
      for (int cs=0; cs<4; ++cs)
        acc[mt][cs] += *(const f32x4*)(rp + (cs*64 + l)*4);
    }
    __syncthreads();
    if (nq == 2){
      #pragma unroll
      for (int cs=0; cs<4; ++cs)
        *(f32x4*)(redA + (cs*64 + l)*4) = acc[mt][cs];
    }
    __syncthreads();
    if (nq == 0){
      #pragma unroll
      for (int cs=0; cs<4; ++cs){
        f32x4 r = *(const f32x4*)(redA + (cs*64 + l)*4);
        f32x4 a = acc[mt][cs] + r;
        const int c = ch*64 + cs*16 + lm;
        const size_t base = ((size_t)(b*128 + c))*NN + m0w + mt*16 + 4*g;
        f32x4 xv = *(const f32x4*)(x + base);
        f32x4 ov;
        #pragma unroll
        for (int i=0;i<4;++i) ov[i] = xv[i] + gm*a[i];
        *(f32x4*)(out + base) = ov;
      }
    }
    __syncthreads();
  }
}

extern "C" void kernel_launch(void* const* d_in, const int* in_sizes, int n_in,
                              void* d_out, int out_size, void* d_ws, size_t ws_size,
                              hipStream_t stream)
{
  const float* x     = (const float*)d_in[0];
  const float* Wf    = (const float*)d_in[1];
  const float* bf    = (const float*)d_in[2];
  const float* Wg    = (const float*)d_in[3];
  const float* bg    = (const float*)d_in[4];
  const float* Wh    = (const float*)d_in[5];
  const float* bh    = (const float*)d_in[6];
  const float* gamma = (const float*)d_in[7];
  float* out = (float*)d_out;

  short* fT   = (short*)d_ws;                    // [B][N][16] bf16 (*log2e)
  short* gT   = fT + (size_t)BB*NN*16;           // [B][N][16] bf16
  short* hP   = gT + (size_t)BB*NN*16;           // [B][128nc][512row][8e] bf16 fragment layout
  float* Lrow = (float*)(hP + (size_t)BB*CC*NN); // [B][N]

  k_proj  <<<BB*64,  256, 0, stream>>>(x, Wf, bf, Wg, bg, Wh, bh, fT, gT, hP);
  k_stats <<<BB*64,  512, 0, stream>>>(fT, gT, Lrow);
  k_attend<<<BB*128, 256, 0, stream>>>(x, fT, gT, hP, Lrow, gamma, out);
}

// Round 17
// 67.572 us; speedup vs baseline: 1.1601x; 1.1601x over previous
//
#include <hip/hip_runtime.h>
#include <hip/hip_bf16.h>

#define BB 8
#define CC 128
#define NN 4096
#define LOG2E 1.44269504088896340736f

typedef __attribute__((ext_vector_type(4))) float f32x4;
typedef __attribute__((ext_vector_type(4))) short s16x4;
typedef __attribute__((ext_vector_type(8))) short s16x8;

__device__ inline short f2bf(float f){
  unsigned u = __float_as_uint(f);
  u += 0x7FFFu + ((u >> 16) & 1u);
  return (short)(u >> 16);
}
// low16 = bf16(e0), high16 = bf16(e1), truncation
__device__ inline unsigned pack2(float e0, float e1){
  return __builtin_amdgcn_perm(__float_as_uint(e1), __float_as_uint(e0), 0x07060302u);
}

// read one MFMA operand fragment from a swizzled LDS tile:
// element (row, c) lives at byte row*256 + ((c>>2)^(row&31))*8 + (c&3)*2
__device__ inline s16x8 frag_read(const char* base, int row, int kk, int g){
  const int m = row & 31;
  const char* rp = base + row*256;
  s16x4 lo = *(const s16x4*)(rp + (((kk*8 + g)     ^ m) << 3));
  s16x4 hi = *(const s16x4*)(rp + (((kk*8 + 4 + g) ^ m) << 3));
  s16x8 r = {lo[0],lo[1],lo[2],lo[3],hi[0],hi[1],hi[2],hi[3]};
  return r;
}

// ---------------- K1: MFMA projections ----------------
__global__ __launch_bounds__(256) void k_proj(
    const float* __restrict__ x,  const float* __restrict__ Wf, const float* __restrict__ bf,
    const float* __restrict__ Wg, const float* __restrict__ bg,
    const float* __restrict__ Wh, const float* __restrict__ bh,
    short* __restrict__ fT, short* __restrict__ gT, short* __restrict__ hP)
{
  __shared__ __align__(16) char sx[16384];
  __shared__ __align__(16) char sw[40960];

  const int blk = blockIdx.x;
  const int b = blk & 7, ntile = blk >> 3;
  const int n0 = ntile * 64;
  const int tid = threadIdx.x;

  // stage x: c-pair packed u32 writes (2 bf16 per ds_write_b32)
  {
    const int cpair = tid >> 4;           // 0..15
    const int nj = (tid & 15) * 4;        // 0..60
    #pragma unroll
    for (int p = 0; p < 4; ++p){
      const int c0 = p*32 + cpair*2;
      f32x4 v0 = *(const f32x4*)(x + ((size_t)(b*128 + c0    ))*NN + n0 + nj);
      f32x4 v1 = *(const f32x4*)(x + ((size_t)(b*128 + c0 + 1))*NN + n0 + nj);
      #pragma unroll
      for (int e = 0; e < 4; ++e){
        const int n = nj + e;
        const int off = n*256 + ((((c0>>2) ^ (n & 31))) << 3) + ((c0 & 3) << 1);
        *(unsigned*)(sx + off) = pack2(v0[e], v1[e]);
      }
    }
  }
  // stage W, bf16 trunc (Wf scaled by log2e)
  {
    #pragma unroll
    for (int p = 0; p < 20; ++p){
      const int id = p*256 + tid;
      const int row = id >> 5;
      const int q = id & 31;
      const float* src; float scale = 1.0f;
      if (row < 16)      { src = Wf + row*128;      scale = LOG2E; }
      else if (row < 32) { src = Wg + (row-16)*128; }
      else               { src = Wh + (row-32)*128; }
      f32x4 v = *(const f32x4*)(src + q*4);
      unsigned u0 = pack2(v[0]*scale, v[1]*scale);
      unsigned u1 = pack2(v[2]*scale, v[3]*scale);
      const int off = row*256 + ((q ^ (row & 31)) << 3);
      *(unsigned long long*)(sw + off) = ((unsigned long long)u1 << 32) | u0;
    }
  }
  __syncthreads();

  const int w = tid >> 6, l = tid & 63;
  const int g = l >> 4, lm = l & 15;
  const int nn = w*16 + lm;
  const int nglob = n0 + w*16 + lm;

  s16x8 xf[4];
  #pragma unroll
  for (int kk = 0; kk < 4; ++kk) xf[kk] = frag_read(sx, nn, kk, g);

  {
    f32x4 acc;
    f32x4 bv = *(const f32x4*)(bf + 4*g);
    #pragma unroll
    for (int i=0;i<4;++i) acc[i] = bv[i] * LOG2E;
    #pragma unroll
    for (int kk = 0; kk < 4; ++kk)
      acc = __builtin_amdgcn_mfma_f32_16x16x32_bf16(frag_read(sw, lm, kk, g), xf[kk], acc, 0,0,0);
    unsigned u0 = pack2(acc[0], acc[1]);
    unsigned u1 = pack2(acc[2], acc[3]);
    *(unsigned long long*)(fT + ((size_t)b*NN + nglob)*16 + 4*g) = ((unsigned long long)u1 << 32) | u0;
  }
  {
    f32x4 acc = *(const f32x4*)(bg + 4*g);
    #pragma unroll
    for (int kk = 0; kk < 4; ++kk)
      acc = __builtin_amdgcn_mfma_f32_16x16x32_bf16(frag_read(sw, 16+lm, kk, g), xf[kk], acc, 0,0,0);
    unsigned u0 = pack2(acc[0], acc[1]);
    unsigned u1 = pack2(acc[2], acc[3]);
    *(unsigned long long*)(gT + ((size_t)b*NN + nglob)*16 + 4*g) = ((unsigned long long)u1 << 32) | u0;
  }
  {
    const int nc  = ntile*2 + (w >> 1);
    const int tau = w & 1;
    #pragma unroll
    for (int ct = 0; ct < 8; ++ct){
      const float bb = bh[ct*16 + lm];
      f32x4 acc = {bb, bb, bb, bb};
      #pragma unroll
      for (int kk = 0; kk < 4; ++kk)
        acc = __builtin_amdgcn_mfma_f32_16x16x32_bf16(xf[kk], frag_read(sw, 32 + ct*16 + lm, kk, g), acc, 0,0,0);
      unsigned u0 = pack2(acc[0], acc[1]);
      unsigned u1 = pack2(acc[2], acc[3]);
      const int row = ct*64 + g*16 + lm;
      *(unsigned long long*)((char*)hP + (((size_t)(b*128 + nc))*512 + row)*16 + tau*8)
          = ((unsigned long long)u1 << 32) | u0;
    }
  }
}

// ---------------- K2: L[n] = -log2( sum_m exp2(S'[n][m]) ) ----------------
// S-MFMA uses K=16 (16x16x16 bf16) — Cp=16 exactly, no zero-padded K slots (R14 win).
__global__ __launch_bounds__(512,4) void k_stats(
    const short* __restrict__ fT, const short* __restrict__ gT, float* __restrict__ Lrow)
{
  __shared__ float sm[2][4][16];
  const int blk = blockIdx.x;
  const int b = blk & 7, ntile = blk >> 3;
  const int tid = threadIdx.x;
  const int w = tid >> 6, l = tid & 63;
  const int g = l >> 4, lm = l & 15;
  const int ns = w & 3, mh = w >> 2;
  const int n0 = ntile*64 + ns*16;
  const f32x4 zero4 = {0.f,0.f,0.f,0.f};

  s16x4 fa = *(const s16x4*)(fT + ((size_t)b*NN + n0 + lm)*16 + 4*g);

  const short* gTb = gT + ((size_t)b*NN + mh*2048 + lm)*16 + 4*g;

  f32x4 rs = {0.f,0.f,0.f,0.f};
  s16x4 gc[4], gn[4];
  #pragma unroll
  for (int j=0;j<4;++j) gc[j] = *(const s16x4*)(gTb + j*256);

  #pragma unroll 1
  for (int it=0; it<32; ++it){
    const int nx = (it < 31) ? it+1 : 31;
    #pragma unroll
    for (int j=0;j<4;++j) gn[j] = *(const s16x4*)(gTb + nx*1024 + j*256);
    #pragma unroll
    for (int j=0;j<4;++j){
      f32x4 d = __builtin_amdgcn_mfma_f32_16x16x16bf16_1k(fa, gc[j], zero4, 0,0,0);
      #pragma unroll
      for (int i=0;i<4;++i) rs[i] += __builtin_amdgcn_exp2f(d[i]);
    }
    #pragma unroll
    for (int j=0;j<4;++j) gc[j] = gn[j];
  }
  #pragma unroll
  for (int i=0;i<4;++i){
    #pragma unroll
    for (int mask=1; mask<16; mask<<=1) rs[i] += __shfl_xor(rs[i], mask);
  }
  if (lm == 0){
    #pragma unroll
    for (int i=0;i<4;++i) sm[mh][ns][4*g+i] = rs[i];
  }
  __syncthreads();
  if (mh == 0 && lm == 0){
    #pragma unroll
    for (int i=0;i<4;++i){
      float z = rs[i] + sm[1][ns][4*g+i];
      Lrow[(size_t)b*NN + n0 + 4*g + i] = -__log2f(z);
    }
  }
}

// ---------------- K3: out = x + gamma * sum_n h[c][n] * exp2(S'[n][m] + L[n]) ----------------
// Best measured config (R13/R15): grid 512 = 8b x 64 mtiles(64 m), block 256 = 4 waves
// (1 m-group x 4 nq) -> 2 blocks/CU. Batched hb loads at iter top, no main-loop
// barriers, setprio, K=32 S-MFMA.
__global__ __launch_bounds__(256,2) void k_attend(
    const float* __restrict__ x, const short* __restrict__ fT, const short* __restrict__ gT,
    const short* __restrict__ hP, const float* __restrict__ Lrow,
    const float* __restrict__ gamma, float* __restrict__ out)
{
  __shared__ __align__(16) char lds[16384];

  const int blk = blockIdx.x;
  const int b = blk & 7, mtile = blk >> 3;     // 0..63
  const int tid = threadIdx.x;
  const int nq = tid >> 6, l = tid & 63;
  const int g = l >> 4, lm = l & 15;
  const int m0w = mtile*64;
  const f32x4 zero4 = {0.f,0.f,0.f,0.f};

  const short* fTb = fT + ((size_t)b*NN + nq*1024 + lm)*16 + 4*g;
  const float* Lb  = Lrow + (size_t)b*NN + nq*1024 + 4*g;
  const char*  hB  = (const char*)hP + (((size_t)(b*128 + nq*32))*512 + l)*16;

  s16x8 gb[4];
  #pragma unroll
  for (int mt=0; mt<4; ++mt){
    s16x4 g4 = *(const s16x4*)(gT + ((size_t)b*NN + m0w + mt*16 + lm)*16 + 4*g);
    s16x8 t = {g4[0],g4[1],g4[2],g4[3],0,0,0,0};
    gb[mt] = t;
  }

  f32x4 acc[4][8];
  #pragma unroll
  for (int mt=0;mt<4;++mt)
    #pragma unroll
    for (int cs=0;cs<8;++cs) acc[mt][cs] = zero4;

  s16x4 fa_c0 = *(const s16x4*)(fTb);
  s16x4 fa_c1 = *(const s16x4*)(fTb + 256);
  f32x4 C0 = *(const f32x4*)(Lb);
  f32x4 C1 = *(const f32x4*)(Lb + 16);

  #pragma unroll 1
  for (int it=0; it<32; ++it){
    const int nx = (it < 31) ? it+1 : 31;

    // h fragments for this chunk: 8 independent coalesced 1KB loads, issued first;
    // the S/exp2/pack phase below covers their L2 latency.
    s16x8 hb[8];
    #pragma unroll
    for (int cs=0; cs<8; ++cs) hb[cs] = *(const s16x8*)(hB + it*8192 + cs*1024);

    // prefetch fa/L for next chunk (clamped, unconditional)
    s16x4 pfa0 = *(const s16x4*)(fTb + nx*512);
    s16x4 pfa1 = *(const s16x4*)(fTb + nx*512 + 256);
    f32x4 pC0  = *(const f32x4*)(Lb + nx*32);
    f32x4 pC1  = *(const f32x4*)(Lb + nx*32 + 16);

    s16x8 fa0 = {fa_c0[0],fa_c0[1],fa_c0[2],fa_c0[3],0,0,0,0};
    s16x8 fa1 = {fa_c1[0],fa_c1[1],fa_c1[2],fa_c1[3],0,0,0,0};

    __builtin_amdgcn_s_setprio(1);
    s16x8 A[4];
    #pragma unroll
    for (int mt=0; mt<4; ++mt){
      f32x4 d0 = __builtin_amdgcn_mfma_f32_16x16x32_bf16(fa0, gb[mt], C0, 0,0,0);
      f32x4 d1 = __builtin_amdgcn_mfma_f32_16x16x32_bf16(fa1, gb[mt], C1, 0,0,0);
      union { unsigned u[4]; s16x8 v; } P;
      P.u[0] = pack2(__builtin_amdgcn_exp2f(d0[0]), __builtin_amdgcn_exp2f(d0[1]));
      P.u[1] = pack2(__builtin_amdgcn_exp2f(d0[2]), __builtin_amdgcn_exp2f(d0[3]));
      P.u[2] = pack2(__builtin_amdgcn_exp2f(d1[0]), __builtin_amdgcn_exp2f(d1[1]));
      P.u[3] = pack2(__builtin_amdgcn_exp2f(d1[2]), __builtin_amdgcn_exp2f(d1[3]));
      A[mt] = P.v;
    }

    #pragma unroll
    for (int cs=0; cs<8; ++cs){
      #pragma unroll
      for (int mt=0; mt<4; ++mt)
        acc[mt][cs] = __builtin_amdgcn_mfma_f32_16x16x32_bf16(A[mt], hb[cs], acc[mt][cs], 0,0,0);
    }
    __builtin_amdgcn_s_setprio(0);

    fa_c0 = pfa0; fa_c1 = pfa1; C0 = pC0; C1 = pC1;
  }

  // 4-way nq reduction in 4 fully-unrolled mt-phases (static acc indexing)
  float* redA = (float*)lds;             // [8 cs][64 lane][4]
  float* redB = (float*)(lds + 8192);
  const float gm = gamma[0];
  #pragma unroll
  for (int mt=0; mt<4; ++mt){
    if (nq == 1 || nq == 3){
      float* rp = (nq==1)? redA : redB;
      #pragma unroll
      for (int cs=0; cs<8; ++cs)
        *(f32x4*)(rp + (cs*64 + l)*4) = acc[mt][cs];
    }
    __syncthreads();
    if (nq == 0 || nq == 2){
      const float* rp = (nq==0)? redA : redB;
      #pragma unroll
      for (int cs=0; cs<8; ++cs)
        acc[mt][cs] += *(const f32x4*)(rp + (cs*64 + l)*4);
    }
    __syncthreads();
    if (nq == 2){
      #pragma unroll
      for (int cs=0; cs<8; ++cs)
        *(f32x4*)(redA + (cs*64 + l)*4) = acc[mt][cs];
    }
    __syncthreads();
    if (nq == 0){
      #pragma unroll
      for (int cs=0; cs<8; ++cs){
        f32x4 r = *(const f32x4*)(redA + (cs*64 + l)*4);
        f32x4 a = acc[mt][cs] + r;
        const int c = cs*16 + lm;
        const size_t base = ((size_t)(b*128 + c))*NN + m0w + mt*16 + 4*g;
        f32x4 xv = *(const f32x4*)(x + base);
        f32x4 ov;
        #pragma unroll
        for (int i=0;i<4;++i) ov[i] = xv[i] + gm*a[i];
        *(f32x4*)(out + base) = ov;
      }
    }
    __syncthreads();
  }
}

extern "C" void kernel_launch(void* const* d_in, const int* in_sizes, int n_in,
                              void* d_out, int out_size, void* d_ws, size_t ws_size,
                              hipStream_t stream)
{
  const float* x     = (const float*)d_in[0];
  const float* Wf    = (const float*)d_in[1];
  const float* bf    = (const float*)d_in[2];
  const float* Wg    = (const float*)d_in[3];
  const float* bg    = (const float*)d_in[4];
  const float* Wh    = (const float*)d_in[5];
  const float* bh    = (const float*)d_in[6];
  const float* gamma = (const float*)d_in[7];
  float* out = (float*)d_out;

  short* fT   = (short*)d_ws;                    // [B][N][16] bf16 (*log2e)
  short* gT   = fT + (size_t)BB*NN*16;           // [B][N][16] bf16
  short* hP   = gT + (size_t)BB*NN*16;           // [B][128nc][512row][8e] bf16 fragment layout
  float* Lrow = (float*)(hP + (size_t)BB*CC*NN); // [B][N]

  k_proj  <<<BB*64, 256, 0, stream>>>(x, Wf, bf, Wg, bg, Wh, bh, fT, gT, hP);
  k_stats <<<BB*64, 512, 0, stream>>>(fT, gT, Lrow);
  k_attend<<<BB*64, 256, 0, stream>>>(x, fT, gT, hP, Lrow, gamma, out);
}